// Round 1
// baseline (362.794 us; speedup 1.0000x reference)
//
#include <hip/hip_runtime.h>

#define DD 160
#define HH 192
#define WW 160
#define VOL (DD * HH * WW)   // 4915200
#define NB 2
#define NC 2

typedef float v2f  __attribute__((ext_vector_type(2)));
// align(4): lets the compiler emit global_load_dwordx2 at 4B-aligned addresses
// (gfx950 supports unaligned global access; worst case it splits = no regression)
typedef float v2fu __attribute__((ext_vector_type(2), aligned(4)));

// 2 consecutive W-voxels per thread. Key change vs prev version: the two x-taps
// of each trilinear corner pair are adjacent floats -> ONE dwordx2 gather per
// (z,y)-corner per channel (16 gathers instead of 32 scalar ones). Clamp
// boundary cases are folded into rebased weights (wA/wB), not value selects.
__global__ __launch_bounds__(256) void warp_kernel(
    const float* __restrict__ x,
    const float* __restrict__ flow,
    float* __restrict__ out)
{
    int t = blockIdx.x * blockDim.x + threadIdx.x;
    int v = t * 2;                       // global voxel index (incl. batch)
    int b = (v >= VOL) ? 1 : 0;
    v -= b * VOL;

    int xw = v % WW;                     // first of 2 x-positions
    int tt = v / WW;
    int yh = tt % HH;
    int zd = tt / HH;

    const float* fb = flow + (size_t)b * 3 * VOL;
    v2f dz2 = __builtin_nontemporal_load((const v2f*)(fb + v));
    v2f dy2 = __builtin_nontemporal_load((const v2f*)(fb + v + VOL));
    v2f dx2 = __builtin_nontemporal_load((const v2f*)(fb + v + 2 * VOL));

    float pz[2] = { zd + dz2.x, zd + dz2.y };
    float py[2] = { yh + dy2.x, yh + dy2.y };
    float px[2] = { xw + dx2.x, (xw + 1) + dx2.y };

    int   idx[2][4];                     // dwordx2 base per (z,y) corner
    float wA[2][4], wB[2][4];            // rebased weights for lanes .x / .y

#pragma unroll
    for (int j = 0; j < 2; ++j) {
        float z0f = floorf(pz[j]), y0f = floorf(py[j]), x0f = floorf(px[j]);
        float fz = pz[j] - z0f, fy = py[j] - y0f, fx = px[j] - x0f;
        int z0 = (int)z0f, y0 = (int)y0f, x0 = (int)x0f;
        int z1 = z0 + 1,  y1 = y0 + 1,  x1 = x0 + 1;

        float wz0 = (z0 >= 0 && z0 < DD) ? (1.0f - fz) : 0.0f;
        float wz1 = (z1 >= 0 && z1 < DD) ? fz : 0.0f;
        float wy0 = (y0 >= 0 && y0 < HH) ? (1.0f - fy) : 0.0f;
        float wy1 = (y1 >= 0 && y1 < HH) ? fy : 0.0f;
        float wx0 = (x0 >= 0 && x0 < WW) ? (1.0f - fx) : 0.0f;
        float wx1 = (x1 >= 0 && x1 < WW) ? fx : 0.0f;

        int z0c = min(max(z0, 0), DD - 1);
        int z1c = min(max(z1, 0), DD - 1);
        int y0c = min(max(y0, 0), HH - 1);
        int y1c = min(max(y1, 0), HH - 1);
        int x0c = min(max(x0, 0), WW - 1);
        int x1c = min(max(x1, 0), WW - 1);

        // 8B load window [base, base+1] always inside the row (base <= W-2),
        // so it never reads past the channel/buffer end.
        int base = min(x0c, WW - 2);

        // Rebase x-weights onto the two loaded lanes. Covers all clamp cases:
        //  normal:       x0c==base, x1c==base+1 -> wA=wx0, wB=wx1
        //  x0 == -1:     both taps at 0         -> wA=wx0+wx1 (wx0 is 0), wB=0
        //  x0 == W-1:    both taps at W-1       -> wA=0, wB=wx0+wx1 (wx1 is 0)
        //  fully OOB:    weights already 0
        float a  = ((x0c == base) ? wx0 : 0.0f) + ((x1c == base) ? wx1 : 0.0f);
        float bb = (wx0 + wx1) - a;

        int p00 = (z0c * HH + y0c) * WW + base;
        int p01 = (z0c * HH + y1c) * WW + base;
        int p10 = (z1c * HH + y0c) * WW + base;
        int p11 = (z1c * HH + y1c) * WW + base;

        float w0 = wz0 * wy0;
        float w1 = wz0 * wy1;
        float w2 = wz1 * wy0;
        float w3 = wz1 * wy1;

        idx[j][0] = p00;  wA[j][0] = w0 * a;  wB[j][0] = w0 * bb;
        idx[j][1] = p01;  wA[j][1] = w1 * a;  wB[j][1] = w1 * bb;
        idx[j][2] = p10;  wA[j][2] = w2 * a;  wB[j][2] = w2 * bb;
        idx[j][3] = p11;  wA[j][3] = w3 * a;  wB[j][3] = w3 * bb;
    }

    const float* xb0 = x + (size_t)b * NC * VOL;
    const float* xb1 = xb0 + VOL;

    float a0[2], a1[2];
#pragma unroll
    for (int j = 0; j < 2; ++j) {
        float s0 = 0.0f, s1 = 0.0f;
#pragma unroll
        for (int k = 0; k < 4; ++k) {
            int ii = idx[j][k];
            v2fu c0 = *(const v2fu*)(xb0 + ii);
            v2fu c1 = *(const v2fu*)(xb1 + ii);
            s0 += wA[j][k] * c0.x + wB[j][k] * c0.y;
            s1 += wA[j][k] * c1.x + wB[j][k] * c1.y;
        }
        a0[j] = s0;
        a1[j] = s1;
    }

    float* ob = out + (size_t)b * NC * VOL;
    v2f r0; r0.x = a0[0]; r0.y = a0[1];
    v2f r1; r1.x = a1[0]; r1.y = a1[1];
    __builtin_nontemporal_store(r0, (v2f*)(ob + v));
    __builtin_nontemporal_store(r1, (v2f*)(ob + v + VOL));
}

extern "C" void kernel_launch(void* const* d_in, const int* in_sizes, int n_in,
                              void* d_out, int out_size, void* d_ws, size_t ws_size,
                              hipStream_t stream) {
    const float* x    = (const float*)d_in[0];
    const float* flow = (const float*)d_in[1];
    float* out        = (float*)d_out;

    int total_threads = NB * VOL / 2;    // 4,915,200
    int block = 256;
    int grid  = (total_threads + block - 1) / block;  // 19200
    warp_kernel<<<grid, block, 0, stream>>>(x, flow, out);
}